// Round 3
// baseline (4655.000 us; speedup 1.0000x reference)
//
#include <hip/hip_runtime.h>
#include <stdint.h>

typedef unsigned short u16;
typedef __attribute__((ext_vector_type(8))) short short8;     // 8 bf16 (MFMA A/B frag)
typedef __attribute__((ext_vector_type(4))) float float4_;    // MFMA C/D frag
typedef __attribute__((ext_vector_type(4))) unsigned short ushort4v;

#define NB 8
#define LL 4096
#define DD 1024
#define CC 64
#define NCH 64   // LL/CC

__device__ __forceinline__ u16 f2bf(float f) {
  union { float f; uint32_t u; } v; v.f = f;
  uint32_t u = v.u;
  return (u16)((u + 0x7fffu + ((u >> 16) & 1u)) >> 16);   // RNE
}
__device__ __forceinline__ float bf2f(u16 h) {
  union { uint32_t u; float f; } v; v.u = ((uint32_t)h) << 16;
  return v.f;
}
__device__ __forceinline__ float4_ mfma16(short8 a, short8 b, float4_ c) {
  return __builtin_amdgcn_mfma_f32_16x16x32_bf16(a, b, c, 0, 0, 0);
}

// ---------------- dtype detect: flag=1 if inputs are bf16, 0 if f32 ----------------
__global__ void k_detect(const uint32_t* __restrict__ X, int* __restrict__ flag) {
  if (threadIdx.x == 0 && blockIdx.x == 0) {
    int votes = 0;
    for (int i = 0; i < 64; ++i) {
      uint32_t w = X[i];
      uint32_t e = (w >> 7) & 0xFF;   // exponent field of the LOW u16 viewed as bf16
      votes += (e > 134 || e < 110) ? 1 : 0;
    }
    // f32 data: low u16 = random mantissa bits -> ~86% votes. bf16 data: ~0 votes.
    *flag = (votes < 8) ? 1 : 0;
  }
}

// ---------------- convert input tensor -> bf16 (dual dtype) ----------------
__global__ __launch_bounds__(256) void k_convert(const void* __restrict__ src, u16* __restrict__ dst,
                                                 long n8, const int* __restrict__ flag) {
  long i = (long)blockIdx.x * 256 + threadIdx.x;   // index of 8-element chunk
  if (i >= n8) return;
  if (*flag) {
    ((short8*)dst)[i] = ((const short8*)src)[i];
  } else {
    const float4_* s = (const float4_*)src;
    float4_ a = s[2 * i], b = s[2 * i + 1];
    short8 o;
#pragma unroll
    for (int j = 0; j < 4; ++j) { o[j] = (short)f2bf(a[j]); o[4 + j] = (short)f2bf(b[j]); }
    ((short8*)dst)[i] = o;
  }
}

// ---------------- big NT GEMM: Out(M x 1024) = A(M x 1024) @ W(1024 x 1024)^T + bias ----------------
// 128x128 tile, BK=64, 256 threads (4 waves). DUAL=true: output dtype keyed off *flag.
template <bool DUAL>
__device__ __forceinline__ void gemm128(const u16* __restrict__ A, const u16* __restrict__ W,
                                        const u16* __restrict__ bias, void* __restrict__ Out,
                                        int m0, int n0, const int* __restrict__ flag) {
  __shared__ __attribute__((aligned(16))) u16 As[128 * 64];
  __shared__ __attribute__((aligned(16))) u16 Bs[128 * 64];
  const int tid = threadIdx.x, lane = tid & 63, wv = tid >> 6;
  float4_ acc[2][8];
#pragma unroll
  for (int i = 0; i < 2; ++i)
#pragma unroll
    for (int j = 0; j < 8; ++j) acc[i][j] = (float4_)0.f;

  for (int kk = 0; kk < DD; kk += 64) {
#pragma unroll
    for (int i = 0; i < 4; ++i) {   // 128 rows x 64 cols = 1024 short8 chunks per tile
      int e = tid + 256 * i;
      int row = e >> 3, col = (e & 7) * 8;
      *(short8*)&As[row * 64 + col] = *(const short8*)(A + (size_t)(m0 + row) * DD + kk + col);
      *(short8*)&Bs[row * 64 + col] = *(const short8*)(W + (size_t)(n0 + row) * DD + kk + col);
    }
    __syncthreads();
#pragma unroll
    for (int ks = 0; ks < 2; ++ks) {
      short8 af[2];
#pragma unroll
      for (int mt = 0; mt < 2; ++mt)
        af[mt] = *(const short8*)&As[(32 * wv + 16 * mt + (lane & 15)) * 64 + ks * 32 + (lane >> 4) * 8];
#pragma unroll
      for (int nt = 0; nt < 8; ++nt) {
        short8 bf = *(const short8*)&Bs[(16 * nt + (lane & 15)) * 64 + ks * 32 + (lane >> 4) * 8];
#pragma unroll
        for (int mt = 0; mt < 2; ++mt) acc[mt][nt] = mfma16(af[mt], bf, acc[mt][nt]);
      }
    }
    __syncthreads();
  }
  const bool obf = DUAL ? (*flag != 0) : true;
#pragma unroll
  for (int mt = 0; mt < 2; ++mt)
#pragma unroll
    for (int nt = 0; nt < 8; ++nt) {
      int rg = m0 + 32 * wv + 16 * mt + ((lane >> 4) << 2);
      int cg = n0 + 16 * nt + (lane & 15);
      float bv = bf2f(bias[cg]);
#pragma unroll
      for (int r = 0; r < 4; ++r) {
        float o = acc[mt][nt][r] + bv;
        if (obf) ((u16*)Out)[(size_t)(rg + r) * DD + cg] = f2bf(o);
        else     ((float*)Out)[(size_t)(rg + r) * DD + cg] = o;
      }
    }
}

__global__ __launch_bounds__(256) void k_gemm_qkv(const u16* __restrict__ X,
    const u16* __restrict__ Wq, const u16* __restrict__ bq,
    const u16* __restrict__ Wk, const u16* __restrict__ bk,
    const u16* __restrict__ Wv, const u16* __restrict__ bv,
    u16* __restrict__ Qo, u16* __restrict__ Ko, u16* __restrict__ Vo) {
  int nb = blockIdx.x;  // 0..23
  int mat = nb >> 3, nt = nb & 7;
  const u16 *W, *bi; u16* O;
  if (mat == 0)      { W = Wq; bi = bq; O = Qo; }
  else if (mat == 1) { W = Wk; bi = bk; O = Ko; }
  else               { W = Wv; bi = bv; O = Vo; }
  gemm128<false>(X, W, bi, O, blockIdx.y * 128, nt * 128, nullptr);
}

__global__ __launch_bounds__(256) void k_gemm_o(const u16* __restrict__ A,
    const u16* __restrict__ Wo, const u16* __restrict__ bo, void* __restrict__ Out,
    const int* __restrict__ flag) {
  gemm128<true>(A, Wo, bo, Out, blockIdx.y * 128, blockIdx.x * 128, flag);
}

// ---------------- prep: per (chunk, batch): beta, T2, U0 (in place over V), A=tril(QK^T); ch0 also W ----------------
__global__ __launch_bounds__(256) void k_prep(const u16* __restrict__ Q, const u16* __restrict__ K,
                                              u16* __restrict__ V /* V in, U0 out (in place) */,
                                              u16* __restrict__ T2g, u16* __restrict__ Aout,
                                              u16* __restrict__ Wch0) {
  const int ch = blockIdx.x, b = blockIdx.y;
  const size_t row0 = (size_t)b * LL + (size_t)ch * CC;
  const int tid = threadIdx.x, lane = tid & 63, wv = tid >> 6;

  __shared__ __attribute__((aligned(16))) float Gs[64 * 65];   // reused as KTs (u16 64x72) in phase B
  __shared__ __attribute__((aligned(16))) float Ts[64 * 65];   // reused as VTs (u16 64x72) in phase B
  __shared__ __attribute__((aligned(16))) u16 Kt[64 * 64];
  __shared__ __attribute__((aligned(16))) u16 Qt[64 * 64];
  __shared__ __attribute__((aligned(16))) u16 T2s[64 * 72];
  __shared__ float betas[64];

  float4_ accG[4], accA[4];
#pragma unroll
  for (int ct = 0; ct < 4; ++ct) { accG[ct] = (float4_)0.f; accA[ct] = (float4_)0.f; }

  // phase A: G = K K^T, Araw = Q K^T  (K-streamed)
  for (int kk = 0; kk < DD; kk += 64) {
#pragma unroll
    for (int i = 0; i < 2; ++i) {   // 64x64 tiles: 512 chunks / 256 threads
      int e = tid + 256 * i;
      int row = e >> 3, col = (e & 7) * 8;
      *(short8*)&Kt[row * 64 + col] = *(const short8*)(K + (row0 + row) * DD + kk + col);
      *(short8*)&Qt[row * 64 + col] = *(const short8*)(Q + (row0 + row) * DD + kk + col);
    }
    __syncthreads();
#pragma unroll
    for (int ks = 0; ks < 2; ++ks) {
      short8 ak = *(const short8*)&Kt[(16 * wv + (lane & 15)) * 64 + ks * 32 + (lane >> 4) * 8];
      short8 aq = *(const short8*)&Qt[(16 * wv + (lane & 15)) * 64 + ks * 32 + (lane >> 4) * 8];
#pragma unroll
      for (int ct = 0; ct < 4; ++ct) {
        short8 bk = *(const short8*)&Kt[(16 * ct + (lane & 15)) * 64 + ks * 32 + (lane >> 4) * 8];
        accG[ct] = mfma16(ak, bk, accG[ct]);
        accA[ct] = mfma16(aq, bk, accA[ct]);
      }
    }
    __syncthreads();
  }
  u16* Abase = Aout + (size_t)(b * NCH + ch) * (CC * CC);
#pragma unroll
  for (int ct = 0; ct < 4; ++ct) {
    int i0 = 16 * wv + ((lane >> 4) << 2);
    int c = 16 * ct + (lane & 15);
#pragma unroll
    for (int r = 0; r < 4; ++r) {
      int i = i0 + r;
      Gs[i * 65 + c] = accG[ct][r];
      Abase[i * 64 + c] = f2bf((c <= i) ? accA[ct][r] : 0.f);
    }
  }
  __syncthreads();
  if (tid < 64) betas[tid] = 1.f / (Gs[tid * 65 + tid] + 1e-6f);
  __syncthreads();
  for (int e = tid; e < 4096; e += 256) {
    int i = e >> 6, c = e & 63;
    Ts[i * 65 + c] = (c < i) ? (-betas[i] * Gs[i * 65 + c]) : 0.f;
  }
  __syncthreads();
  // forward substitution (reference exact recurrence), wave 0 only
  for (int i = 1; i < 64; ++i) {
    float rv = 0.f, acc = 0.f;
    if (tid < 64) {
      rv = Ts[i * 65 + tid];
      for (int j = 1; j < i; ++j) {
        float a = __shfl(rv, j);
        acc += a * Ts[j * 65 + tid];
      }
    }
    __syncthreads();
    if (tid < i) Ts[i * 65 + tid] = rv + acc;
    __syncthreads();
  }
  if (tid < 64) Ts[tid * 65 + tid] += 1.f;
  __syncthreads();
  u16* t2base = T2g + (size_t)(b * NCH + ch) * (CC * CC);
  for (int e = tid; e < 4096; e += 256) {   // T2[i][j] = T[i][j]*beta[j]
    int i = e >> 6, j = e & 63;
    u16 val = f2bf(Ts[i * 65 + j] * betas[j]);
    T2s[i * 72 + j] = val;
    t2base[e] = val;
  }
  __syncthreads();

  // phase B: U0 = T2 @ V written over V; if ch==0 also W = T2 @ K into Wch0
  u16* KTs = (u16*)Gs;  // 64 x 72
  u16* VTs = (u16*)Ts;  // 64 x 72
  for (int kk = 0; kk < DD; kk += 64) {
#pragma unroll
    for (int rep = 0; rep < 2; ++rep) {   // transpose V (and K) tile into LDS
      int t = tid >> 2;
      int c0 = (tid & 3) * 8 + rep * 32;
      short8 vv = *(const short8*)(V + (row0 + t) * DD + kk + c0);
#pragma unroll
      for (int e = 0; e < 8; ++e) VTs[(c0 + e) * 72 + t] = (u16)vv[e];
      if (ch == 0) {
        short8 vk = *(const short8*)(K + (row0 + t) * DD + kk + c0);
#pragma unroll
        for (int e = 0; e < 8; ++e) KTs[(c0 + e) * 72 + t] = (u16)vk[e];
      }
    }
    __syncthreads();
    float4_ accU[4], accW[4];
#pragma unroll
    for (int ct = 0; ct < 4; ++ct) { accU[ct] = (float4_)0.f; accW[ct] = (float4_)0.f; }
#pragma unroll
    for (int ks = 0; ks < 2; ++ks) {
      short8 a2 = *(const short8*)&T2s[(16 * wv + (lane & 15)) * 72 + ks * 32 + (lane >> 4) * 8];
#pragma unroll
      for (int ct = 0; ct < 4; ++ct) {
        short8 bu = *(const short8*)&VTs[(16 * ct + (lane & 15)) * 72 + ks * 32 + (lane >> 4) * 8];
        accU[ct] = mfma16(a2, bu, accU[ct]);
      }
      if (ch == 0) {
#pragma unroll
        for (int ct = 0; ct < 4; ++ct) {
          short8 bw = *(const short8*)&KTs[(16 * ct + (lane & 15)) * 72 + ks * 32 + (lane >> 4) * 8];
          accW[ct] = mfma16(a2, bw, accW[ct]);
        }
      }
    }
#pragma unroll
    for (int ct = 0; ct < 4; ++ct) {
      int i0 = 16 * wv + ((lane >> 4) << 2);
      int c = kk + 16 * ct + (lane & 15);
#pragma unroll
      for (int r = 0; r < 4; ++r) {
        V[(row0 + i0 + r) * DD + c] = f2bf(accU[ct][r]);     // U0 over V (cols kk only; safe)
        if (ch == 0)
          Wch0[((size_t)b * CC + i0 + r) * DD + c] = f2bf(accW[ct][r]);
      }
    }
    __syncthreads();
  }
}

// ---------------- scan step 1: u = U0 - W@S and Oqs = Q@S (shared f32 S^T staging) ----------------
__global__ __launch_bounds__(256) void k_scan1(const u16* __restrict__ Q, const u16* __restrict__ Wch,
                                               const u16* __restrict__ U0, const float* __restrict__ STf,
                                               u16* __restrict__ uT, float* __restrict__ Oqs, int ch) {
  const int nt = blockIdx.x, b = blockIdx.y;
  const size_t row0 = (size_t)b * LL + (size_t)ch * CC;
  const int tid = threadIdx.x, lane = tid & 63, wv = tid >> 6;
  __shared__ __attribute__((aligned(16))) u16 Wsh[64 * 64];
  __shared__ __attribute__((aligned(16))) u16 Qsh[64 * 64];
  __shared__ __attribute__((aligned(16))) u16 Ssh[64 * 64];
  const int dc0 = nt * 64;
  const u16* wbase = Wch + ((size_t)((ch & 1) * NB + b) * CC) * DD;
  float4_ aw[4], aq[4];
#pragma unroll
  for (int ct = 0; ct < 4; ++ct) { aw[ct] = (float4_)0.f; aq[ct] = (float4_)0.f; }
  for (int kk = 0; kk < DD; kk += 64) {
#pragma unroll
    for (int i = 0; i < 2; ++i) {
      int e = tid + 256 * i;
      int row = e >> 3, col = (e & 7) * 8;
      *(short8*)&Wsh[row * 64 + col] = *(const short8*)(wbase + (size_t)row * DD + kk + col);
      *(short8*)&Qsh[row * 64 + col] = *(const short8*)(Q + (row0 + row) * DD + kk + col);
      const float* sp = STf + ((size_t)b * DD + dc0 + row) * DD + kk + col;
      float4_ x0 = *(const float4_*)sp;
      float4_ x1 = *(const float4_*)(sp + 4);
      short8 s;
#pragma unroll
      for (int j = 0; j < 4; ++j) { s[j] = (short)f2bf(x0[j]); s[4 + j] = (short)f2bf(x1[j]); }
      *(short8*)&Ssh[row * 64 + col] = s;
    }
    __syncthreads();
#pragma unroll
    for (int ks = 0; ks < 2; ++ks) {
      short8 afw = *(const short8*)&Wsh[(16 * wv + (lane & 15)) * 64 + ks * 32 + (lane >> 4) * 8];
      short8 afq = *(const short8*)&Qsh[(16 * wv + (lane & 15)) * 64 + ks * 32 + (lane >> 4) * 8];
#pragma unroll
      for (int ct = 0; ct < 4; ++ct) {
        short8 bf = *(const short8*)&Ssh[(16 * ct + (lane & 15)) * 64 + ks * 32 + (lane >> 4) * 8];
        aw[ct] = mfma16(afw, bf, aw[ct]);
        aq[ct] = mfma16(afq, bf, aq[ct]);
      }
    }
    __syncthreads();
  }
#pragma unroll
  for (int ct = 0; ct < 4; ++ct) {
    int dc = dc0 + 16 * ct + (lane & 15);
    int t0 = 16 * wv + ((lane >> 4) << 2);
    ushort4v pk;
#pragma unroll
    for (int r = 0; r < 4; ++r) {
      pk[r] = f2bf(bf2f(U0[(row0 + t0 + r) * DD + dc]) - aw[ct][r]);
      Oqs[((size_t)b * CC + t0 + r) * DD + dc] = aq[ct][r];
    }
    *(ushort4v*)&uT[((size_t)b * DD + dc) * CC + t0] = pk;
  }
}

// ---------------- scan step 2: S^T += (K^T u)^T ; o = A@u + Oqs -> Opre (over Q) ; W_{ch+1} ----------------
__global__ __launch_bounds__(256) void k_scan2(const u16* __restrict__ K, const u16* __restrict__ uT,
                                               const u16* __restrict__ Aall, const float* __restrict__ Oqs,
                                               float* __restrict__ STf, u16* __restrict__ Opre,
                                               const u16* __restrict__ T2g, u16* __restrict__ Wch, int ch) {
  __shared__ __attribute__((aligned(16))) u16 smem[128 * 72 + 128 * 64];
  const int tid = threadIdx.x, lane = tid & 63, wv = tid >> 6;
  const int bid = blockIdx.x;
  if (bid < 512) {  // S update, 128x128 tile of (dj, dc)
    u16* KTs = smem;              // 128 x 72 (K^T, t-contig)
    u16* uTs = smem + 128 * 72;   // 128 x 64
    const int b = bid >> 6, mi = (bid >> 3) & 7, ni = bid & 7;
    const int dj0 = mi * 128, dc0 = ni * 128;
    const size_t row0 = (size_t)b * LL + (size_t)ch * CC;
#pragma unroll
    for (int rep = 0; rep < 4; ++rep) {   // transpose K chunk tile into LDS
      int t = tid >> 2;
      int c0 = ((tid & 3) + rep * 4) * 8;
      short8 v = *(const short8*)(K + (row0 + t) * DD + dj0 + c0);
#pragma unroll
      for (int e = 0; e < 8; ++e) KTs[(c0 + e) * 72 + t] = (u16)v[e];
    }
#pragma unroll
    for (int i = 0; i < 4; ++i) {   // uT slab: 128 rows x 64
      int e = tid + 256 * i;
      int row = e >> 3, col = (e & 7) * 8;
      *(short8*)&uTs[row * 64 + col] = *(const short8*)(uT + ((size_t)b * DD + dc0 + row) * CC + col);
    }
    __syncthreads();
    float4_ acc[2][8];
#pragma unroll
    for (int i = 0; i < 2; ++i)
#pragma unroll
      for (int j = 0; j < 8; ++j) acc[i][j] = (float4_)0.f;
#pragma unroll
    for (int ks = 0; ks < 2; ++ks) {
      short8 af[2];
#pragma unroll
      for (int mt = 0; mt < 2; ++mt)
        af[mt] = *(const short8*)&KTs[(32 * wv + 16 * mt + (lane & 15)) * 72 + ks * 32 + (lane >> 4) * 8];
#pragma unroll
      for (int nt = 0; nt < 8; ++nt) {
        short8 bf = *(const short8*)&uTs[(16 * nt + (lane & 15)) * 64 + ks * 32 + (lane >> 4) * 8];
#pragma unroll
        for (int mt = 0; mt < 2; ++mt) acc[mt][nt] = mfma16(af[mt], bf, acc[mt][nt]);
      }
    }
#pragma unroll
    for (int mt = 0; mt < 2; ++mt)
#pragma unroll
      for (int nt = 0; nt < 8; ++nt) {
        int dc = dc0 + 16 * nt + (lane & 15);
        int dj = dj0 + 32 * wv + 16 * mt + ((lane >> 4) << 2);
        float* p = &STf[((size_t)b * DD + dc) * DD + dj];
        float4_ old = *(const float4_*)p;
#pragma unroll
        for (int r = 0; r < 4; ++r) old[r] += acc[mt][nt][r];
        *(float4_*)p = old;
      }
  } else if (bid < 640) {  // o = A@u + Oqs -> Opre (overwrites Q rows of this chunk)
    const int idx = bid - 512;
    const int b = idx >> 4, nt2 = idx & 15;
    u16* Ash = smem;
    u16* uSh = smem + 64 * 64;
    const u16* Abase = Aall + (size_t)(b * NCH + ch) * (CC * CC);
    const u16* ubase = uT + ((size_t)b * DD + nt2 * 64) * CC;
#pragma unroll
    for (int i = 0; i < 2; ++i) {
      int e = tid + 256 * i;
      int row = e >> 3, col = (e & 7) * 8;
      *(short8*)&Ash[row * 64 + col] = *(const short8*)(Abase + row * 64 + col);
      *(short8*)&uSh[row * 64 + col] = *(const short8*)(ubase + (size_t)row * CC + col);
    }
    __syncthreads();
    float4_ acc[4];
#pragma unroll
    for (int ct = 0; ct < 4; ++ct) acc[ct] = (float4_)0.f;
#pragma unroll
    for (int ks = 0; ks < 2; ++ks) {
      short8 af = *(const short8*)&Ash[(16 * wv + (lane & 15)) * 64 + ks * 32 + (lane >> 4) * 8];
#pragma unroll
      for (int ct = 0; ct < 4; ++ct) {
        short8 bf = *(const short8*)&uSh[(16 * ct + (lane & 15)) * 64 + ks * 32 + (lane >> 4) * 8];
        acc[ct] = mfma16(af, bf, acc[ct]);
      }
    }
    const size_t orow0 = (size_t)b * LL + (size_t)ch * CC;
#pragma unroll
    for (int ct = 0; ct < 4; ++ct) {
      int dc = nt2 * 64 + 16 * ct + (lane & 15);
      int t0 = 16 * wv + ((lane >> 4) << 2);
#pragma unroll
      for (int r = 0; r < 4; ++r) {
        float o = acc[ct][r] + Oqs[((size_t)b * CC + t0 + r) * DD + dc];
        Opre[(orow0 + t0 + r) * DD + dc] = f2bf(o);
      }
    }
  } else {  // W_{ch+1} = T2_{ch+1} @ K_{ch+1}, 64x64 col-panel per block
    if (ch + 1 >= NCH) return;
    const int idx = bid - 640;
    const int b = idx >> 4, nt = idx & 15;
    const int dj0 = nt * 64;
    const int nx = ch + 1;
    const size_t row0n = (size_t)b * LL + (size_t)nx * CC;
    u16* KTs = smem;   // 64 x 72
#pragma unroll
    for (int rep = 0; rep < 2; ++rep) {
      int t = tid >> 2;
      int c0 = (tid & 3) * 8 + rep * 32;
      short8 v = *(const short8*)(K + (row0n + t) * DD + dj0 + c0);
#pragma unroll
      for (int e = 0; e < 8; ++e) KTs[(c0 + e) * 72 + t] = (u16)v[e];
    }
    __syncthreads();
    const u16* t2base = T2g + (size_t)(b * NCH + nx) * (CC * CC);
    float4_ acc[4];
#pragma unroll
    for (int ct = 0; ct < 4; ++ct) acc[ct] = (float4_)0.f;
#pragma unroll
    for (int ks = 0; ks < 2; ++ks) {
      short8 a2 = *(const short8*)(t2base + (16 * wv + (lane & 15)) * 64 + ks * 32 + (lane >> 4) * 8);
#pragma unroll
      for (int ct = 0; ct < 4; ++ct) {
        short8 bf = *(const short8*)&KTs[(16 * ct + (lane & 15)) * 72 + ks * 32 + (lane >> 4) * 8];
        acc[ct] = mfma16(a2, bf, acc[ct]);
      }
    }
    u16* wbase = Wch + ((size_t)(((ch + 1) & 1) * NB + b) * CC) * DD;
#pragma unroll
    for (int ct = 0; ct < 4; ++ct) {
      int c = dj0 + 16 * ct + (lane & 15);
      int t0 = 16 * wv + ((lane >> 4) << 2);
#pragma unroll
      for (int r = 0; r < 4; ++r)
        wbase[(size_t)(t0 + r) * DD + c] = f2bf(acc[ct][r]);
    }
  }
}

extern "C" void kernel_launch(void* const* d_in, const int* in_sizes, int n_in,
                              void* d_out, int out_size, void* d_ws, size_t ws_size,
                              hipStream_t stream) {
  (void)in_sizes; (void)n_in; (void)out_size; (void)ws_size;
  const void* X  = d_in[0];
  // d_in[1] = chunk (=64), hard-coded
  const void* Wq = d_in[2]; const void* bq = d_in[3];
  const void* Wk = d_in[4]; const void* bk = d_in[5];
  const void* Wv = d_in[6]; const void* bv = d_in[7];
  const void* Wo = d_in[8]; const void* bo = d_in[9];

  char* ws = (char*)d_ws;
  int* flag = (int*)ws;
  char* p = ws + 256;
  const size_t E2 = (size_t)NB * LL * DD * 2;                  // 64 MiB per bf16 (B,L,D)
  u16* xb   = (u16*)p; p += E2;                                // X bf16
  u16* wqb  = (u16*)p; p += (size_t)DD * DD * 2;               // 2 MiB each
  u16* wkb  = (u16*)p; p += (size_t)DD * DD * 2;
  u16* wvb  = (u16*)p; p += (size_t)DD * DD * 2;
  u16* wob  = (u16*)p; p += (size_t)DD * DD * 2;
  u16* bqb  = (u16*)p; p += 4096;                              // 2 KiB slots (aligned)
  u16* bkb  = (u16*)p; p += 4096;
  u16* bvb  = (u16*)p; p += 4096;
  u16* bob  = (u16*)p; p += 4096;
  u16* q_ws = (u16*)p; p += E2;                                // Q; Opre overwrites per chunk
  u16* k_ws = (u16*)p; p += E2;                                // K
  u16* v_ws = (u16*)p; p += E2;                                // V -> U0 in place
  u16* t2_ws = (u16*)p; p += (size_t)NB * NCH * CC * CC * 2;   // 4 MiB
  u16* a_ws  = (u16*)p; p += (size_t)NB * NCH * CC * CC * 2;   // 4 MiB
  float* stf = (float*)p; p += (size_t)NB * DD * DD * 4;       // 32 MiB (S^T master f32)
  u16* wch   = (u16*)p;  p += (size_t)2 * NB * CC * DD * 2;    // 2 MiB (W ping-pong)
  u16* ut_ws = (u16*)p;  p += (size_t)NB * DD * CC * 2;        // 1 MiB (u transposed)
  float* oqs = (float*)p;                                      // 2 MiB (Q@S f32)
  // total ~310 MiB

  hipMemsetAsync(stf, 0, (size_t)NB * DD * DD * 4, stream);

  k_detect<<<1, 64, 0, stream>>>((const uint32_t*)X, flag);
  const long nX = (long)NB * LL * DD / 8;   // 4M chunks
  k_convert<<<(nX + 255) / 256, 256, 0, stream>>>(X, xb, nX, flag);
  const long nW = (long)DD * DD / 8;        // 128K chunks
  k_convert<<<(nW + 255) / 256, 256, 0, stream>>>(Wq, wqb, nW, flag);
  k_convert<<<(nW + 255) / 256, 256, 0, stream>>>(Wk, wkb, nW, flag);
  k_convert<<<(nW + 255) / 256, 256, 0, stream>>>(Wv, wvb, nW, flag);
  k_convert<<<(nW + 255) / 256, 256, 0, stream>>>(Wo, wob, nW, flag);
  const long nBias = DD / 8;                // 128 chunks
  k_convert<<<1, 256, 0, stream>>>(bq, bqb, nBias, flag);
  k_convert<<<1, 256, 0, stream>>>(bk, bkb, nBias, flag);
  k_convert<<<1, 256, 0, stream>>>(bv, bvb, nBias, flag);
  k_convert<<<1, 256, 0, stream>>>(bo, bob, nBias, flag);

  k_gemm_qkv<<<dim3(24, 256), 256, 0, stream>>>(xb, wqb, bqb, wkb, bkb, wvb, bvb, q_ws, k_ws, v_ws);
  k_prep<<<dim3(64, 8), 256, 0, stream>>>(q_ws, k_ws, v_ws, t2_ws, a_ws, wch);
  for (int ch = 0; ch < NCH; ++ch) {
    k_scan1<<<dim3(16, 8), 256, 0, stream>>>(q_ws, wch, v_ws, stf, ut_ws, oqs, ch);
    k_scan2<<<dim3(768), 256, 0, stream>>>(k_ws, ut_ws, a_ws, oqs, stf, q_ws, t2_ws, wch, ch);
  }
  k_gemm_o<<<dim3(8, 256), 256, 0, stream>>>(q_ws, wob, bob, d_out, flag);
}